// Round 5
// baseline (454.839 us; speedup 1.0000x reference)
//
#include <hip/hip_runtime.h>
#include <math.h>

#define NHEAD 16
#define TSEQ  2048
#define BATCH 2
#define DM    2048

typedef __attribute__((ext_vector_type(8))) short bf16x8;
typedef __attribute__((ext_vector_type(4))) float f32x4;

__device__ __forceinline__ short f2bf(float f) {
    unsigned u = __builtin_bit_cast(unsigned, f);
    u += 0x7fff + ((u >> 16) & 1);          // RNE
    return (short)(u >> 16);
}
__device__ __forceinline__ float bf2f(short s) {
    unsigned u = ((unsigned)(unsigned short)s) << 16;
    return __builtin_bit_cast(float, u);
}
__device__ __forceinline__ void gload_lds16(const void* g, void* l) {
    __builtin_amdgcn_global_load_lds(
        (const __attribute__((address_space(1))) unsigned int*)g,
        (__attribute__((address_space(3))) unsigned int*)l, 16, 0, 0);
}

// ---------------------------------------------------------------------------
// merged fp32->bf16 casts: x (8.39M), w_qkv (12.58M), w_out (4.19M)
// ---------------------------------------------------------------------------
__global__ __launch_bounds__(256)
void cast_all(const float* __restrict__ x, short* __restrict__ xb,
              const float* __restrict__ wq, short* __restrict__ wqb,
              const float* __restrict__ wo, short* __restrict__ wob)
{
    int bid = blockIdx.x;
    const float* src; short* dst; int lb;
    if (bid < 4096)       { src = x;  dst = xb;  lb = bid; }
    else if (bid < 10240) { src = wq; dst = wqb; lb = bid - 4096; }
    else                  { src = wo; dst = wob; lb = bid - 10240; }
    int i = (lb * 256 + threadIdx.x) * 8;
    float4 a = *(const float4*)(src + i);
    float4 b = *(const float4*)(src + i + 4);
    bf16x8 o;
    o[0]=f2bf(a.x); o[1]=f2bf(a.y); o[2]=f2bf(a.z); o[3]=f2bf(a.w);
    o[4]=f2bf(b.x); o[5]=f2bf(b.y); o[6]=f2bf(b.z); o[7]=f2bf(b.w);
    *(bf16x8*)(dst + i) = o;
}

// ---------------------------------------------------------------------------
// QKV GEMM (m97 structure) + fused bias + RoPE + fragment repack epilogue.
// q additionally scaled by 2048^-0.5 * log2(e) so attention softmax can use
// raw exp2 (v_exp_f32) with no per-score multiply.
// ---------------------------------------------------------------------------
__global__ __launch_bounds__(256)
void gemm_qkv_rope(const short* __restrict__ A, const short* __restrict__ W,
                   const float* __restrict__ bias, short* __restrict__ qfrag,
                   short* __restrict__ kfrag, short* __restrict__ vfrag)
{
    const int K = 2048;
    __shared__ short sm[17408];          // union: staging 16384 | tile 17408
    short* As = sm;                      // 128*64
    short* Bs = sm + 8192;
    const int tid = threadIdx.x;
    const int lane = tid & 63, w = tid >> 6;
    const int lane15 = lane & 15, quad = lane >> 4;
    const int wr = w >> 1, wc = w & 1;
    const int row0 = blockIdx.y * 128, col0 = blockIdx.x * 128;

    f32x4 acc[4][4];
    #pragma unroll
    for (int mi = 0; mi < 4; ++mi)
        #pragma unroll
        for (int ni = 0; ni < 4; ++ni)
            acc[mi][ni] = (f32x4){0.f, 0.f, 0.f, 0.f};

    for (int kt = 0; kt < K; kt += 64) {
        __syncthreads();
        #pragma unroll
        for (int i = 0; i < 4; ++i) {
            int ci = i * 256 + tid;
            int row = ci >> 3, lc = ci & 7;
            int gc = lc ^ (row & 7);
            gload_lds16(A + (size_t)(row0 + row) * K + kt + gc * 8, As + ci * 8);
            gload_lds16(W + (size_t)(col0 + row) * K + kt + gc * 8, Bs + ci * 8);
        }
        __syncthreads();
        #pragma unroll
        for (int kc = 0; kc < 2; ++kc) {
            bf16x8 af[4], bfr[4];
            #pragma unroll
            for (int mi = 0; mi < 4; ++mi) {
                int r = wr * 64 + mi * 16 + lane15;
                af[mi] = *(const bf16x8*)(As + r * 64 + ((kc * 4 + quad) ^ (r & 7)) * 8);
            }
            #pragma unroll
            for (int ni = 0; ni < 4; ++ni) {
                int r = wc * 64 + ni * 16 + lane15;
                bfr[ni] = *(const bf16x8*)(Bs + r * 64 + ((kc * 4 + quad) ^ (r & 7)) * 8);
            }
            #pragma unroll
            for (int mi = 0; mi < 4; ++mi)
                #pragma unroll
                for (int ni = 0; ni < 4; ++ni)
                    acc[mi][ni] = __builtin_amdgcn_mfma_f32_16x16x32_bf16(
                        af[mi], bfr[ni], acc[mi][ni], 0, 0, 0);
        }
    }

    // ---- epilogue ----
    const int head = col0 / 384;
    const int type = (col0 % 384) >> 7;      // 0=q 1=k 2=v
    const int b    = row0 >> 11;
    const int t0g  = row0 & 2047;
    const int bh   = b * NHEAD + head;

    __syncthreads();
    #pragma unroll
    for (int ni = 0; ni < 4; ++ni) {
        int d = wc * 64 + ni * 16 + lane15;
        float bv = bias[col0 + d];
        #pragma unroll
        for (int mi = 0; mi < 4; ++mi) {
            int rowb = wr * 64 + mi * 16 + quad * 4;
            #pragma unroll
            for (int r = 0; r < 4; ++r)
                sm[(rowb + r) * 136 + d] = f2bf(acc[mi][ni][r] + bv);
        }
    }
    __syncthreads();

    if (type < 2) {   // q or k: rope + frag store
        // q: 2048^-0.5 * log2(e)  (exp2-domain softmax)
        const float sc = (type == 0) ? 0.031879357813f : 1.0f;
        short* dst = (type == 0 ? qfrag : kfrag) + (size_t)bh * 262144;
        #pragma unroll
        for (int it = 0; it < 4; ++it) {
            int c = it * 256 + tid;
            int l15 = c & 15, q_ = (c >> 4) & 3, kc = (c >> 6) & 1, rowhi = c >> 7;
            int lrow = rowhi * 16 + l15;
            int t = t0g + lrow;
            bf16x8 a8 = *(const bf16x8*)(sm + lrow * 136 + kc * 32 + q_ * 8);
            bf16x8 b8 = *(const bf16x8*)(sm + lrow * 136 + kc * 32 + q_ * 8 + 64);
            bf16x8 oa, ob;
            #pragma unroll
            for (int j = 0; j < 8; ++j) {
                int d = kc * 32 + q_ * 8 + j;
                float trev = exp2f(-(float)d * (13.287712379549449f / 64.0f))
                             * 0.15915494309189535f;
                float ang = (float)t * trev;
                float fr = ang - floorf(ang);
                float sn, cs;
                __sincosf(fr * 6.283185307179586f, &sn, &cs);
                float va = bf2f(a8[j]), vb = bf2f(b8[j]);
                oa[j] = f2bf((va * cs - vb * sn) * sc);
                ob[j] = f2bf((va * sn + vb * cs) * sc);
            }
            size_t base = (size_t)((t0g >> 4) + rowhi) * 2048 + (q_ * 16 + l15) * 8;
            *(bf16x8*)(dst + base + kc * 512)        = oa;
            *(bf16x8*)(dst + base + kc * 512 + 1024) = ob;
        }
    } else {          // v: transpose to vfrag
        short* dst = vfrag + (size_t)bh * 262144;
        #pragma unroll
        for (int it = 0; it < 8; ++it) {
            int c = it * 256 + tid;
            int lane_ = c & 63, rest = c >> 6;
            int q_ = lane_ >> 4, l15 = lane_ & 15;
            int dt = rest & 7, kc2 = (rest >> 3) & 1, kbt = rest >> 4;
            int d = dt * 16 + l15;
            bf16x8 v;
            #pragma unroll
            for (int j = 0; j < 8; ++j)
                v[j] = sm[(kbt * 64 + kc2 * 32 + q_ * 8 + j) * 136 + d];
            *(bf16x8*)(dst + (size_t)((t0g >> 6) + kbt) * 8192
                        + dt * 1024 + kc2 * 512 + lane_ * 8) = v;
        }
    }
}

// ---------------------------------------------------------------------------
// bf16 MFMA GEMM (NT) for out-projection (fp32 out).
// ---------------------------------------------------------------------------
__global__ __launch_bounds__(256)
void gemm_out(const short* __restrict__ A, const short* __restrict__ W,
              const float* __restrict__ bias, float* __restrict__ Cout,
              int N, int K)
{
    __shared__ short As[128 * 64];
    __shared__ short Bs[128 * 64];
    const int tid = threadIdx.x;
    const int lane = tid & 63, w = tid >> 6;
    const int lane15 = lane & 15, quad = lane >> 4;
    const int wr = w >> 1, wc = w & 1;
    const int row0 = blockIdx.y * 128, col0 = blockIdx.x * 128;

    f32x4 acc[4][4];
    #pragma unroll
    for (int mi = 0; mi < 4; ++mi)
        #pragma unroll
        for (int ni = 0; ni < 4; ++ni)
            acc[mi][ni] = (f32x4){0.f, 0.f, 0.f, 0.f};

    for (int kt = 0; kt < K; kt += 64) {
        __syncthreads();
        #pragma unroll
        for (int i = 0; i < 4; ++i) {
            int ci = i * 256 + tid;
            int row = ci >> 3, lc = ci & 7;
            int gc = lc ^ (row & 7);
            gload_lds16(A + (size_t)(row0 + row) * K + kt + gc * 8, As + ci * 8);
            gload_lds16(W + (size_t)(col0 + row) * K + kt + gc * 8, Bs + ci * 8);
        }
        __syncthreads();
        #pragma unroll
        for (int kc = 0; kc < 2; ++kc) {
            bf16x8 af[4], bfr[4];
            #pragma unroll
            for (int mi = 0; mi < 4; ++mi) {
                int r = wr * 64 + mi * 16 + lane15;
                af[mi] = *(const bf16x8*)(As + r * 64 + ((kc * 4 + quad) ^ (r & 7)) * 8);
            }
            #pragma unroll
            for (int ni = 0; ni < 4; ++ni) {
                int r = wc * 64 + ni * 16 + lane15;
                bfr[ni] = *(const bf16x8*)(Bs + r * 64 + ((kc * 4 + quad) ^ (r & 7)) * 8);
            }
            #pragma unroll
            for (int mi = 0; mi < 4; ++mi)
                #pragma unroll
                for (int ni = 0; ni < 4; ++ni)
                    acc[mi][ni] = __builtin_amdgcn_mfma_f32_16x16x32_bf16(
                        af[mi], bfr[ni], acc[mi][ni], 0, 0, 0);
        }
    }

    #pragma unroll
    for (int mi = 0; mi < 4; ++mi)
        #pragma unroll
        for (int ni = 0; ni < 4; ++ni) {
            int col = col0 + wc * 64 + ni * 16 + lane15;
            float bv = bias[col];
            #pragma unroll
            for (int r = 0; r < 4; ++r) {
                int row = row0 + wr * 64 + mi * 16 + quad * 4 + r;
                Cout[(size_t)row * N + col] = acc[mi][ni][r] + bv;
            }
        }
}

// ---------------------------------------------------------------------------
// Flash attention, pipelined 2-barrier schedule:
//   softmax(kb) -> syncA(drain DMA kb+1) -> QK(kb+1) -> PV(kb) -> syncB
//   -> DMA(kb+2).
// QK(kb+1) is issued BEFORE PV(kb): PV's MFMAs drain in the matrix pipe
// while the wave runs softmax(kb+1); softmax stalls only on QK(kb+1).
// exp2-domain softmax (log2e folded into q scale). P roundtrips a per-wave
// 16-row LDS buffer (in-order DS pipe, compiler-managed waits).
// ---------------------------------------------------------------------------
__global__ __launch_bounds__(256)
void attn4(const short* __restrict__ qfrag, const short* __restrict__ kfrag,
           const short* __restrict__ vfrag, short* __restrict__ attnb)
{
    __shared__ short KV[2][16384];        // per buf: K 16KB | V 16KB
    __shared__ short Pb[4][1152];         // per wave: 16 q x stride 72
    const int tid = threadIdx.x;
    const int lane = tid & 63, w = tid >> 6;
    const int lane15 = lane & 15, quad = lane >> 4;
    const int g = (blockIdx.x + blockIdx.y) & 15;
    const int qb = blockIdx.z ? (15 - g) : g;
    const int h = blockIdx.y, b = blockIdx.z;
    const int bh = b * NHEAD + h;
    const int q0 = qb * 128;
    short* Pw = Pb[w];

    bf16x8 qf[2][4];
    {
        const short* qp = qfrag + (size_t)bh * 262144
                        + (size_t)(qb * 8 + w * 2) * 2048 + lane * 8;
        #pragma unroll
        for (int nq = 0; nq < 2; ++nq)
            #pragma unroll
            for (int kc = 0; kc < 4; ++kc)
                qf[nq][kc] = *(const bf16x8*)(qp + nq * 2048 + kc * 512);
    }

    f32x4 acc[8][2];
    #pragma unroll
    for (int dt = 0; dt < 8; ++dt)
        #pragma unroll
        for (int nq = 0; nq < 2; ++nq)
            acc[dt][nq] = (f32x4){0.f, 0.f, 0.f, 0.f};
    float m_s[2] = {-3e38f, -3e38f}, l_s[2] = {0.f, 0.f};

    const short* kf_src = kfrag + (size_t)bh * 262144;
    const short* vf_src = vfrag + (size_t)bh * 262144;
    const int kb_max = 2 * qb + 1;
    const int qtop = q0 + w * 32 + 31;
    const int diag0 = (q0 + w * 32) >> 6;

    auto dma = [&](int kbn, short* dst) {
        const short* ks = kf_src + (size_t)kbn * 8192;
        const short* vs = vf_src + (size_t)kbn * 8192;
        #pragma unroll
        for (int i = 0; i < 4; ++i) {
            int ci = i * 256 + tid;
            gload_lds16(ks + ci * 8, dst + ci * 8);
            gload_lds16(vs + ci * 8, dst + 8192 + ci * 8);
        }
    };

    f32x4 st[2][4];
    auto qk = [&](const short* Ks) {
        #pragma unroll
        for (int nq = 0; nq < 2; ++nq)
            #pragma unroll
            for (int mi = 0; mi < 4; ++mi)
                st[nq][mi] = (f32x4){0.f, 0.f, 0.f, 0.f};
        #pragma unroll
        for (int mi = 0; mi < 4; ++mi) {
            bf16x8 kf4[4];
            #pragma unroll
            for (int kc = 0; kc < 4; ++kc)
                kf4[kc] = *(const bf16x8*)(Ks + ((mi * 4 + kc) * 64 + lane) * 8);
            #pragma unroll
            for (int kc = 0; kc < 4; ++kc)
                #pragma unroll
                for (int nq = 0; nq < 2; ++nq)
                    st[nq][mi] = __builtin_amdgcn_mfma_f32_16x16x32_bf16(
                        kf4[kc], qf[nq][kc], st[nq][mi], 0, 0, 0);
        }
    };

    // prologue: DMA(0), drain, DMA(1) in flight, QK(0)
    dma(0, KV[0]);
    __syncthreads();
    dma(1, KV[1]);
    qk(KV[0]);

    for (int kb = 0; kb <= kb_max; ++kb) {
        const short* Vs = KV[kb & 1] + 8192;
        const bool live = (kb * 64 <= qtop);
        bf16x8 pbr[2][2];

        if (live) {
            if (kb >= diag0) {
                #pragma unroll
                for (int nq = 0; nq < 2; ++nq) {
                    int qg = q0 + w * 32 + nq * 16 + lane15;
                    #pragma unroll
                    for (int mi = 0; mi < 4; ++mi)
                        #pragma unroll
                        for (int r = 0; r < 4; ++r)
                            if (kb * 64 + mi * 16 + quad * 4 + r > qg)
                                st[nq][mi][r] = -3e38f;
                }
            }
            #pragma unroll
            for (int nq = 0; nq < 2; ++nq) {
                float mt = st[nq][0][0];
                #pragma unroll
                for (int mi = 0; mi < 4; ++mi)
                    #pragma unroll
                    for (int r = 0; r < 4; ++r)
                        mt = fmaxf(mt, st[nq][mi][r]);
                mt = fmaxf(mt, __shfl_xor(mt, 16));
                mt = fmaxf(mt, __shfl_xor(mt, 32));
                float mn = fmaxf(m_s[nq], mt);
                float alpha = __builtin_amdgcn_exp2f(m_s[nq] - mn);
                m_s[nq] = mn;
                float sum = 0.f;
                #pragma unroll
                for (int mi = 0; mi < 4; ++mi)
                    #pragma unroll
                    for (int r = 0; r < 4; ++r) {
                        float p = __builtin_amdgcn_exp2f(st[nq][mi][r] - mn);
                        st[nq][mi][r] = p;
                        sum += p;
                    }
                sum += __shfl_xor(sum, 16);
                sum += __shfl_xor(sum, 32);
                l_s[nq] = l_s[nq] * alpha + sum;
                #pragma unroll
                for (int dt = 0; dt < 8; ++dt) {
                    acc[dt][nq][0] *= alpha; acc[dt][nq][1] *= alpha;
                    acc[dt][nq][2] *= alpha; acc[dt][nq][3] *= alpha;
                }
                short* pr = Pw + lane15 * 72 + quad * 4;
                #pragma unroll
                for (int mi = 0; mi < 4; ++mi) {
                    unsigned lo = (unsigned)(unsigned short)f2bf(st[nq][mi][0])
                                | ((unsigned)(unsigned short)f2bf(st[nq][mi][1]) << 16);
                    unsigned hi = (unsigned)(unsigned short)f2bf(st[nq][mi][2])
                                | ((unsigned)(unsigned short)f2bf(st[nq][mi][3]) << 16);
                    *(unsigned*)(pr + mi * 16)     = lo;
                    *(unsigned*)(pr + mi * 16 + 2) = hi;
                }
                #pragma unroll
                for (int kc2 = 0; kc2 < 2; ++kc2)
                    pbr[nq][kc2] = *(const bf16x8*)
                        (Pw + lane15 * 72 + kc2 * 32 + quad * 8);
            }
        }

        if (kb < kb_max) {
            __syncthreads();                        // syncA: DMA(kb+1) drained
            if ((kb + 1) * 64 <= qtop)
                qk(KV[(kb + 1) & 1]);               // QK ahead of PV
        }

        if (live) {
            #pragma unroll
            for (int dt = 0; dt < 8; ++dt)
                #pragma unroll
                for (int kc2 = 0; kc2 < 2; ++kc2) {
                    bf16x8 vf = *(const bf16x8*)(Vs + ((dt * 2 + kc2) * 64 + lane) * 8);
                    #pragma unroll
                    for (int nq = 0; nq < 2; ++nq)
                        acc[dt][nq] = __builtin_amdgcn_mfma_f32_16x16x32_bf16(
                            vf, pbr[nq][kc2], acc[dt][nq], 0, 0, 0);
                }
        }

        if (kb + 2 <= kb_max) {
            __syncthreads();                        // syncB: buf[kb&1] free
            dma(kb + 2, KV[kb & 1]);
        }
    }

    // epilogue: O^T/l -> LDS transpose -> coalesced bf16 store
    __syncthreads();
    short* Eb = KV[0];                    // 128 x 136
    #pragma unroll
    for (int nq = 0; nq < 2; ++nq) {
        float inv = 1.f / l_s[nq];
        int qrow = w * 32 + nq * 16 + lane15;
        #pragma unroll
        for (int dt = 0; dt < 8; ++dt) {
            unsigned lo = (unsigned)(unsigned short)f2bf(acc[dt][nq][0] * inv)
                        | ((unsigned)(unsigned short)f2bf(acc[dt][nq][1] * inv) << 16);
            unsigned hi = (unsigned)(unsigned short)f2bf(acc[dt][nq][2] * inv)
                        | ((unsigned)(unsigned short)f2bf(acc[dt][nq][3] * inv) << 16);
            *(unsigned*)(Eb + qrow * 136 + dt * 16 + quad * 4)     = lo;
            *(unsigned*)(Eb + qrow * 136 + dt * 16 + quad * 4 + 2) = hi;
        }
    }
    __syncthreads();
    {
        int r = tid >> 1, half = tid & 1;
        short* orow = attnb + (size_t)(b * TSEQ + q0 + r) * DM + h * 128 + half * 64;
        #pragma unroll
        for (int i = 0; i < 8; ++i)
            *(bf16x8*)(orow + i * 8) =
                *(const bf16x8*)(Eb + r * 136 + half * 64 + i * 8);
    }
}

// ---------------------------------------------------------------------------
extern "C" void kernel_launch(void* const* d_in, const int* in_sizes, int n_in,
                              void* d_out, int out_size, void* d_ws, size_t ws_size,
                              hipStream_t stream)
{
    const float* x     = (const float*)d_in[0];
    const float* w_qkv = (const float*)d_in[1];
    const float* b_qkv = (const float*)d_in[2];
    const float* w_out = (const float*)d_in[3];
    const float* b_out = (const float*)d_in[4];
    float* out = (float*)d_out;

    char* ws = (char*)d_ws;
    short* xb    = (short*)(ws);                 // 16.78 MB (reused as attnb)
    short* wqkvb = (short*)(ws + 16777216);      // 25.17 MB
    short* woutb = (short*)(ws + 41943040);      //  8.39 MB
    short* qfrag = (short*)(ws + 50331648);      // 16.78 MB
    short* kfrag = (short*)(ws + 67108864);      // 16.78 MB
    short* vfrag = (short*)(ws + 83886080);      // 16.78 MB  (total 100.66 MB)
    short* attnb = xb;                           // x dead after QKV GEMM

    cast_all<<<12288, 256, 0, stream>>>(x, xb, w_qkv, wqkvb, w_out, woutb);

    {   // qkv GEMM + bias + rope + fragment repack
        dim3 g2(48, 32);
        gemm_qkv_rope<<<g2, 256, 0, stream>>>(xb, wqkvb, b_qkv, qfrag, kfrag, vfrag);
    }
    {   // flash attention
        dim3 g2(16, NHEAD, BATCH);
        attn4<<<g2, 256, 0, stream>>>(qfrag, kfrag, vfrag, attnb);
    }
    {   // out = attn @ w_out^T + b_out
        dim3 g2(16, 32);
        gemm_out<<<g2, 256, 0, stream>>>(attnb, woutb, b_out, out, 2048, 2048);
    }
}

// Round 6
// 389.977 us; speedup vs baseline: 1.1663x; 1.1663x over previous
//
#include <hip/hip_runtime.h>
#include <math.h>

#define NHEAD 16
#define TSEQ  2048
#define BATCH 2
#define DM    2048

typedef __attribute__((ext_vector_type(8))) short bf16x8;
typedef __attribute__((ext_vector_type(4))) float f32x4;

__device__ __forceinline__ short f2bf(float f) {
    unsigned u = __builtin_bit_cast(unsigned, f);
    u += 0x7fff + ((u >> 16) & 1);          // RNE
    return (short)(u >> 16);
}
__device__ __forceinline__ float bf2f(short s) {
    unsigned u = ((unsigned)(unsigned short)s) << 16;
    return __builtin_bit_cast(float, u);
}
__device__ __forceinline__ void gload_lds16(const void* g, void* l) {
    __builtin_amdgcn_global_load_lds(
        (const __attribute__((address_space(1))) unsigned int*)g,
        (__attribute__((address_space(3))) unsigned int*)l, 16, 0, 0);
}

// ---------------------------------------------------------------------------
// merged fp32->bf16 casts: x (8.39M), w_qkv (12.58M), w_out (4.19M)
// ---------------------------------------------------------------------------
__global__ __launch_bounds__(256)
void cast_all(const float* __restrict__ x, short* __restrict__ xb,
              const float* __restrict__ wq, short* __restrict__ wqb,
              const float* __restrict__ wo, short* __restrict__ wob)
{
    int bid = blockIdx.x;
    const float* src; short* dst; int lb;
    if (bid < 4096)       { src = x;  dst = xb;  lb = bid; }
    else if (bid < 10240) { src = wq; dst = wqb; lb = bid - 4096; }
    else                  { src = wo; dst = wob; lb = bid - 10240; }
    int i = (lb * 256 + threadIdx.x) * 8;
    float4 a = *(const float4*)(src + i);
    float4 b = *(const float4*)(src + i + 4);
    bf16x8 o;
    o[0]=f2bf(a.x); o[1]=f2bf(a.y); o[2]=f2bf(a.z); o[3]=f2bf(a.w);
    o[4]=f2bf(b.x); o[5]=f2bf(b.y); o[6]=f2bf(b.z); o[7]=f2bf(b.w);
    *(bf16x8*)(dst + i) = o;
}

// ---------------------------------------------------------------------------
// QKV GEMM (m97 structure) + fused bias + RoPE + fragment repack epilogue.
// q additionally scaled by 2048^-0.5 * log2(e) (exp2-domain softmax).
// ---------------------------------------------------------------------------
__global__ __launch_bounds__(256)
void gemm_qkv_rope(const short* __restrict__ A, const short* __restrict__ W,
                   const float* __restrict__ bias, short* __restrict__ qfrag,
                   short* __restrict__ kfrag, short* __restrict__ vfrag)
{
    const int K = 2048;
    __shared__ short sm[17408];          // union: staging 16384 | tile 17408
    short* As = sm;                      // 128*64
    short* Bs = sm + 8192;
    const int tid = threadIdx.x;
    const int lane = tid & 63, w = tid >> 6;
    const int lane15 = lane & 15, quad = lane >> 4;
    const int wr = w >> 1, wc = w & 1;
    const int row0 = blockIdx.y * 128, col0 = blockIdx.x * 128;

    f32x4 acc[4][4];
    #pragma unroll
    for (int mi = 0; mi < 4; ++mi)
        #pragma unroll
        for (int ni = 0; ni < 4; ++ni)
            acc[mi][ni] = (f32x4){0.f, 0.f, 0.f, 0.f};

    for (int kt = 0; kt < K; kt += 64) {
        __syncthreads();
        #pragma unroll
        for (int i = 0; i < 4; ++i) {
            int ci = i * 256 + tid;
            int row = ci >> 3, lc = ci & 7;
            int gc = lc ^ (row & 7);
            gload_lds16(A + (size_t)(row0 + row) * K + kt + gc * 8, As + ci * 8);
            gload_lds16(W + (size_t)(col0 + row) * K + kt + gc * 8, Bs + ci * 8);
        }
        __syncthreads();
        #pragma unroll
        for (int kc = 0; kc < 2; ++kc) {
            bf16x8 af[4], bfr[4];
            #pragma unroll
            for (int mi = 0; mi < 4; ++mi) {
                int r = wr * 64 + mi * 16 + lane15;
                af[mi] = *(const bf16x8*)(As + r * 64 + ((kc * 4 + quad) ^ (r & 7)) * 8);
            }
            #pragma unroll
            for (int ni = 0; ni < 4; ++ni) {
                int r = wc * 64 + ni * 16 + lane15;
                bfr[ni] = *(const bf16x8*)(Bs + r * 64 + ((kc * 4 + quad) ^ (r & 7)) * 8);
            }
            #pragma unroll
            for (int mi = 0; mi < 4; ++mi)
                #pragma unroll
                for (int ni = 0; ni < 4; ++ni)
                    acc[mi][ni] = __builtin_amdgcn_mfma_f32_16x16x32_bf16(
                        af[mi], bfr[ni], acc[mi][ni], 0, 0, 0);
        }
    }

    // ---- epilogue ----
    const int head = col0 / 384;
    const int type = (col0 % 384) >> 7;      // 0=q 1=k 2=v
    const int b    = row0 >> 11;
    const int t0g  = row0 & 2047;
    const int bh   = b * NHEAD + head;

    __syncthreads();
    #pragma unroll
    for (int ni = 0; ni < 4; ++ni) {
        int d = wc * 64 + ni * 16 + lane15;
        float bv = bias[col0 + d];
        #pragma unroll
        for (int mi = 0; mi < 4; ++mi) {
            int rowb = wr * 64 + mi * 16 + quad * 4;
            #pragma unroll
            for (int r = 0; r < 4; ++r)
                sm[(rowb + r) * 136 + d] = f2bf(acc[mi][ni][r] + bv);
        }
    }
    __syncthreads();

    if (type < 2) {   // q or k: rope + frag store
        const float sc = (type == 0) ? 0.031879357813f : 1.0f;  // 2048^-.5*log2e
        short* dst = (type == 0 ? qfrag : kfrag) + (size_t)bh * 262144;
        #pragma unroll
        for (int it = 0; it < 4; ++it) {
            int c = it * 256 + tid;
            int l15 = c & 15, q_ = (c >> 4) & 3, kc = (c >> 6) & 1, rowhi = c >> 7;
            int lrow = rowhi * 16 + l15;
            int t = t0g + lrow;
            bf16x8 a8 = *(const bf16x8*)(sm + lrow * 136 + kc * 32 + q_ * 8);
            bf16x8 b8 = *(const bf16x8*)(sm + lrow * 136 + kc * 32 + q_ * 8 + 64);
            bf16x8 oa, ob;
            #pragma unroll
            for (int j = 0; j < 8; ++j) {
                int d = kc * 32 + q_ * 8 + j;
                float trev = exp2f(-(float)d * (13.287712379549449f / 64.0f))
                             * 0.15915494309189535f;
                float ang = (float)t * trev;
                float fr = ang - floorf(ang);
                float sn, cs;
                __sincosf(fr * 6.283185307179586f, &sn, &cs);
                float va = bf2f(a8[j]), vb = bf2f(b8[j]);
                oa[j] = f2bf((va * cs - vb * sn) * sc);
                ob[j] = f2bf((va * sn + vb * cs) * sc);
            }
            size_t base = (size_t)((t0g >> 4) + rowhi) * 2048 + (q_ * 16 + l15) * 8;
            *(bf16x8*)(dst + base + kc * 512)        = oa;
            *(bf16x8*)(dst + base + kc * 512 + 1024) = ob;
        }
    } else {          // v: transpose to vfrag
        short* dst = vfrag + (size_t)bh * 262144;
        #pragma unroll
        for (int it = 0; it < 8; ++it) {
            int c = it * 256 + tid;
            int lane_ = c & 63, rest = c >> 6;
            int q_ = lane_ >> 4, l15 = lane_ & 15;
            int dt = rest & 7, kc2 = (rest >> 3) & 1, kbt = rest >> 4;
            int d = dt * 16 + l15;
            bf16x8 v;
            #pragma unroll
            for (int j = 0; j < 8; ++j)
                v[j] = sm[(kbt * 64 + kc2 * 32 + q_ * 8 + j) * 136 + d];
            *(bf16x8*)(dst + (size_t)((t0g >> 6) + kbt) * 8192
                        + dt * 1024 + kc2 * 512 + lane_ * 8) = v;
        }
    }
}

// ---------------------------------------------------------------------------
// bf16 MFMA GEMM (NT) for out-projection (fp32 out).
// ---------------------------------------------------------------------------
__global__ __launch_bounds__(256)
void gemm_out(const short* __restrict__ A, const short* __restrict__ W,
              const float* __restrict__ bias, float* __restrict__ Cout,
              int N, int K)
{
    __shared__ short As[128 * 64];
    __shared__ short Bs[128 * 64];
    const int tid = threadIdx.x;
    const int lane = tid & 63, w = tid >> 6;
    const int lane15 = lane & 15, quad = lane >> 4;
    const int wr = w >> 1, wc = w & 1;
    const int row0 = blockIdx.y * 128, col0 = blockIdx.x * 128;

    f32x4 acc[4][4];
    #pragma unroll
    for (int mi = 0; mi < 4; ++mi)
        #pragma unroll
        for (int ni = 0; ni < 4; ++ni)
            acc[mi][ni] = (f32x4){0.f, 0.f, 0.f, 0.f};

    for (int kt = 0; kt < K; kt += 64) {
        __syncthreads();
        #pragma unroll
        for (int i = 0; i < 4; ++i) {
            int ci = i * 256 + tid;
            int row = ci >> 3, lc = ci & 7;
            int gc = lc ^ (row & 7);
            gload_lds16(A + (size_t)(row0 + row) * K + kt + gc * 8, As + ci * 8);
            gload_lds16(W + (size_t)(col0 + row) * K + kt + gc * 8, Bs + ci * 8);
        }
        __syncthreads();
        #pragma unroll
        for (int kc = 0; kc < 2; ++kc) {
            bf16x8 af[4], bfr[4];
            #pragma unroll
            for (int mi = 0; mi < 4; ++mi) {
                int r = wr * 64 + mi * 16 + lane15;
                af[mi] = *(const bf16x8*)(As + r * 64 + ((kc * 4 + quad) ^ (r & 7)) * 8);
            }
            #pragma unroll
            for (int ni = 0; ni < 4; ++ni) {
                int r = wc * 64 + ni * 16 + lane15;
                bfr[ni] = *(const bf16x8*)(Bs + r * 64 + ((kc * 4 + quad) ^ (r & 7)) * 8);
            }
            #pragma unroll
            for (int mi = 0; mi < 4; ++mi)
                #pragma unroll
                for (int ni = 0; ni < 4; ++ni)
                    acc[mi][ni] = __builtin_amdgcn_mfma_f32_16x16x32_bf16(
                        af[mi], bfr[ni], acc[mi][ni], 0, 0, 0);
        }
    }

    #pragma unroll
    for (int mi = 0; mi < 4; ++mi)
        #pragma unroll
        for (int ni = 0; ni < 4; ++ni) {
            int col = col0 + wc * 64 + ni * 16 + lane15;
            float bv = bias[col];
            #pragma unroll
            for (int r = 0; r < 4; ++r) {
                int row = row0 + wr * 64 + mi * 16 + quad * 4 + r;
                Cout[(size_t)row * N + col] = acc[mi][ni][r] + bv;
            }
        }
}

// ---------------------------------------------------------------------------
// Flash attention, TLP-maximized: 64-q blocks (grid 1024 = 4 blocks/CU),
// wave = 16 q rows. Single-buffered KV (32 KB) + XOR-swizzled P scratch
// (8 KB) = 40960 B -> 4 blocks/CU LDS-limited as well. 16 waves/CU at
// independent loop phases hide the serial chain. exp2-domain softmax.
// qb = z ? 31-g : g balances per-CU cost.
// ---------------------------------------------------------------------------
__global__ __launch_bounds__(256)
void attn5(const short* __restrict__ qfrag, const short* __restrict__ kfrag,
           const short* __restrict__ vfrag, short* __restrict__ attnb)
{
    __shared__ short KV[16384];           // K 8192 | V 8192 shorts
    __shared__ short Pb[4][1024];         // per wave: 16 q x 64 key, swizzled
    const int tid = threadIdx.x;
    const int lane = tid & 63, w = tid >> 6;
    const int lane15 = lane & 15, quad = lane >> 4;
    const int g = (blockIdx.x + blockIdx.y) & 31;
    const int qb = blockIdx.z ? (31 - g) : g;
    const int h = blockIdx.y, b = blockIdx.z;
    const int bh = b * NHEAD + h;
    const int q0 = qb * 64;
    short* Pw = Pb[w];
    short* Ks = KV;
    short* Vs = KV + 8192;

    // Q fragments: wave's 16 rows = q0 + w*16 + lane15
    bf16x8 qf[4];
    {
        const short* qp = qfrag + (size_t)bh * 262144
                        + (size_t)(qb * 4 + w) * 2048 + lane * 8;
        #pragma unroll
        for (int kc = 0; kc < 4; ++kc)
            qf[kc] = *(const bf16x8*)(qp + kc * 512);
    }

    f32x4 acc[8];
    #pragma unroll
    for (int dt = 0; dt < 8; ++dt) acc[dt] = (f32x4){0.f, 0.f, 0.f, 0.f};
    float m_s = -3e38f, l_s = 0.f;

    const short* kf_src = kfrag + (size_t)bh * 262144;
    const short* vf_src = vfrag + (size_t)bh * 262144;
    const int qg = q0 + w * 16 + lane15;      // this lane's q row

    for (int kb = 0; kb <= qb; ++kb) {
        if (kb) __syncthreads();              // prev iter done with KV
        #pragma unroll
        for (int i = 0; i < 4; ++i) {
            int ci = i * 256 + tid;
            gload_lds16(kf_src + (size_t)kb * 8192 + ci * 8, Ks + ci * 8);
            gload_lds16(vf_src + (size_t)kb * 8192 + ci * 8, Vs + ci * 8);
        }
        __syncthreads();

        // S^T = K Q^T : 64 keys x 16 q
        f32x4 st[4];
        #pragma unroll
        for (int mi = 0; mi < 4; ++mi) st[mi] = (f32x4){0.f, 0.f, 0.f, 0.f};
        #pragma unroll
        for (int mi = 0; mi < 4; ++mi) {
            bf16x8 kf4[4];
            #pragma unroll
            for (int kc = 0; kc < 4; ++kc)
                kf4[kc] = *(const bf16x8*)(Ks + ((mi * 4 + kc) * 64 + lane) * 8);
            #pragma unroll
            for (int kc = 0; kc < 4; ++kc)
                st[mi] = __builtin_amdgcn_mfma_f32_16x16x32_bf16(
                    kf4[kc], qf[kc], st[mi], 0, 0, 0);
        }

        if (kb == qb) {   // diagonal: causal mask (key on quad*4+r, q on lane15)
            #pragma unroll
            for (int mi = 0; mi < 4; ++mi)
                #pragma unroll
                for (int r = 0; r < 4; ++r)
                    if (kb * 64 + mi * 16 + quad * 4 + r > qg)
                        st[mi][r] = -3e38f;
        }

        // online softmax (exp2 domain; state per lane, uniform across quads)
        float mt = st[0][0];
        #pragma unroll
        for (int mi = 0; mi < 4; ++mi)
            #pragma unroll
            for (int r = 0; r < 4; ++r) mt = fmaxf(mt, st[mi][r]);
        mt = fmaxf(mt, __shfl_xor(mt, 16));
        mt = fmaxf(mt, __shfl_xor(mt, 32));
        float mn = fmaxf(m_s, mt);
        float alpha = __builtin_amdgcn_exp2f(m_s - mn);
        m_s = mn;
        float sum = 0.f;
        #pragma unroll
        for (int mi = 0; mi < 4; ++mi)
            #pragma unroll
            for (int r = 0; r < 4; ++r) {
                float p = __builtin_amdgcn_exp2f(st[mi][r] - mn);
                st[mi][r] = p;
                sum += p;
            }
        sum += __shfl_xor(sum, 16);
        sum += __shfl_xor(sum, 32);
        l_s = l_s * alpha + sum;
        #pragma unroll
        for (int dt = 0; dt < 8; ++dt) {
            acc[dt][0] *= alpha; acc[dt][1] *= alpha;
            acc[dt][2] *= alpha; acc[dt][3] *= alpha;
        }

        // P (C-layout) -> swizzled per-wave LDS -> B-operand fragments
        {
            short* pr = Pw + lane15 * 64 + (quad & 1) * 4;
            #pragma unroll
            for (int mi = 0; mi < 4; ++mi) {
                unsigned lo = (unsigned)(unsigned short)f2bf(st[mi][0])
                            | ((unsigned)(unsigned short)f2bf(st[mi][1]) << 16);
                unsigned hi = (unsigned)(unsigned short)f2bf(st[mi][2])
                            | ((unsigned)(unsigned short)f2bf(st[mi][3]) << 16);
                int swz = (mi * 2 + (quad >> 1)) ^ (lane15 & 7);
                *(uint2*)(pr + swz * 8) = make_uint2(lo, hi);
            }
        }
        bf16x8 pbr[2];
        #pragma unroll
        for (int kc2 = 0; kc2 < 2; ++kc2)
            pbr[kc2] = *(const bf16x8*)
                (Pw + lane15 * 64 + (((kc2 * 4 + quad) ^ (lane15 & 7)) * 8));

        // O^T += V^T P^T
        #pragma unroll
        for (int dt = 0; dt < 8; ++dt)
            #pragma unroll
            for (int kc2 = 0; kc2 < 2; ++kc2) {
                bf16x8 vf = *(const bf16x8*)(Vs + ((dt * 2 + kc2) * 64 + lane) * 8);
                acc[dt] = __builtin_amdgcn_mfma_f32_16x16x32_bf16(
                    vf, pbr[kc2], acc[dt], 0, 0, 0);
            }
    }

    // epilogue: O^T/l -> LDS transpose [64 q][136 d] -> coalesced bf16 store
    __syncthreads();
    short* Eb = KV;
    {
        float inv = 1.f / l_s;
        int qrow = w * 16 + lane15;
        #pragma unroll
        for (int dt = 0; dt < 8; ++dt) {
            unsigned lo = (unsigned)(unsigned short)f2bf(acc[dt][0] * inv)
                        | ((unsigned)(unsigned short)f2bf(acc[dt][1] * inv) << 16);
            unsigned hi = (unsigned)(unsigned short)f2bf(acc[dt][2] * inv)
                        | ((unsigned)(unsigned short)f2bf(acc[dt][3] * inv) << 16);
            *(uint2*)(Eb + qrow * 136 + dt * 16 + quad * 4) = make_uint2(lo, hi);
        }
    }
    __syncthreads();
    {
        int r = tid >> 2, part = tid & 3;
        short* orow = attnb + (size_t)(b * TSEQ + q0 + r) * DM + h * 128 + part * 32;
        #pragma unroll
        for (int i = 0; i < 4; ++i)
            *(bf16x8*)(orow + i * 8) =
                *(const bf16x8*)(Eb + r * 136 + part * 32 + i * 8);
    }
}

// ---------------------------------------------------------------------------
extern "C" void kernel_launch(void* const* d_in, const int* in_sizes, int n_in,
                              void* d_out, int out_size, void* d_ws, size_t ws_size,
                              hipStream_t stream)
{
    const float* x     = (const float*)d_in[0];
    const float* w_qkv = (const float*)d_in[1];
    const float* b_qkv = (const float*)d_in[2];
    const float* w_out = (const float*)d_in[3];
    const float* b_out = (const float*)d_in[4];
    float* out = (float*)d_out;

    char* ws = (char*)d_ws;
    short* xb    = (short*)(ws);                 // 16.78 MB (reused as attnb)
    short* wqkvb = (short*)(ws + 16777216);      // 25.17 MB
    short* woutb = (short*)(ws + 41943040);      //  8.39 MB
    short* qfrag = (short*)(ws + 50331648);      // 16.78 MB
    short* kfrag = (short*)(ws + 67108864);      // 16.78 MB
    short* vfrag = (short*)(ws + 83886080);      // 16.78 MB  (total 100.66 MB)
    short* attnb = xb;                           // x dead after QKV GEMM

    cast_all<<<12288, 256, 0, stream>>>(x, xb, w_qkv, wqkvb, w_out, woutb);

    {   // qkv GEMM + bias + rope + fragment repack
        dim3 g2(48, 32);
        gemm_qkv_rope<<<g2, 256, 0, stream>>>(xb, wqkvb, b_qkv, qfrag, kfrag, vfrag);
    }
    {   // flash attention: 64-q tiles, 1024 blocks
        dim3 g2(32, NHEAD, BATCH);
        attn5<<<g2, 256, 0, stream>>>(qfrag, kfrag, vfrag, attnb);
    }
    {   // out = attn @ w_out^T + b_out
        dim3 g2(16, 32);
        gemm_out<<<g2, 256, 0, stream>>>(attnb, woutb, b_out, out, 2048, 2048);
    }
}